// Round 3
// baseline (1069.605 us; speedup 1.0000x reference)
//
#include <hip/hip_runtime.h>

#define LSEQ 4096
#define NPOS 8192
#define NBLK 512            // 16 positions per block, 4 per wave

__device__ __forceinline__ float silu_f(float x){ return x / (1.f + __expf(-x)); }
__device__ __forceinline__ float softplus_f(float x){
  return fmaxf(x, 0.f) + log1pf(__expf(-fabsf(x)));
}

// ---- grid barrier: device-scope atomics, one slot per phase ------------
__device__ __forceinline__ void gsync(unsigned* bar, int slot){
  __syncthreads();
  if (threadIdx.x == 0){
    __threadfence();                       // release: L2 writeback (agent scope)
    atomicAdd(&bar[slot], 1u);             // device-scope by default on CDNA
    int guard = 0;
    while (__hip_atomic_load(&bar[slot], __ATOMIC_ACQUIRE,
                             __HIP_MEMORY_SCOPE_AGENT) < (unsigned)NBLK){
      __builtin_amdgcn_s_sleep(2);
      if (++guard > (1 << 22)) break;      // no-hang escape hatch
    }
    __threadfence();                       // acquire: L1/L2 invalidate
  }
  __syncthreads();
}

// ---- transpose weights, A = -exp(A_log) --------------------------------
__global__ __launch_bounds__(256) void k_prep(
    const float* __restrict__ ipw, const float* __restrict__ xpw,
    const float* __restrict__ dtw, const float* __restrict__ opw,
    const float* __restrict__ w1, const float* __restrict__ w2,
    const float* __restrict__ w3, const float* __restrict__ alog,
    float* __restrict__ ipT, float* __restrict__ xpT,
    float* __restrict__ dtT, float* __restrict__ opT,
    float* __restrict__ w1T, float* __restrict__ w2T,
    float* __restrict__ w3T, float* __restrict__ Aneg)
{
  int t = blockIdx.x * 256 + threadIdx.x;
  if (t < 16384){ int o = t >> 6, c = t & 63; ipT[c * 256 + o] = ipw[t]; }
  if (t < 8192){ int o = t >> 7, d = t & 127; xpT[d * 64 + o] = xpw[t]; }
  if (t < 4096){ int d = t >> 5, r = t & 31; dtT[r * 128 + d] = dtw[t]; }
  if (t < 8192){ int o = t >> 7, d = t & 127; opT[d * 64 + o] = opw[t]; }
  if (t < 4096){ int o = t >> 6, c = t & 63;
                 w1T[c*64+o] = w1[t]; w2T[c*64+o] = w2[t]; w3T[c*64+o] = w3[t]; }
  if (t < 2048){ Aneg[t] = -__expf(alog[t]); }
}

// ---- the whole network in one persistent kernel ------------------------
// block = 256 thr (4 waves), owns 16 consecutive positions; wave owns 4.
// lane owns d_inner rows d0=lane, d1=64+lane and d_model channel c=lane.
// h stays in VGPRs across all 6 mamba blocks; only xcp ping-pongs through
// global (conv1d halo needs neighbors) with a grid barrier per block.
__global__ __launch_bounds__(256, 2) void k_fused(
    const float* __restrict__ rgb, const float* __restrict__ dte,
    const float* __restrict__ b1, const float* __restrict__ b2,
    const float* __restrict__ w1T, const float* __restrict__ w2T,
    const float* __restrict__ normw, const float* __restrict__ ipT,
    const float* __restrict__ xpT, const float* __restrict__ dtT,
    const float* __restrict__ opT, const float* __restrict__ Aneg,
    const float* __restrict__ c1w, const float* __restrict__ c1b,
    const float* __restrict__ dtb, const float* __restrict__ Dpw,
    const float* __restrict__ w3T, const float* __restrict__ b3,
    float* __restrict__ xcp0, float* __restrict__ xcp1,
    unsigned* __restrict__ bar,
    float* __restrict__ outc, float* __restrict__ hout)
{
  __shared__ __align__(16) float inT[2][64][16];   // staged input tiles
  __shared__ __align__(16) float xcl[4][4][128];   // conv-out (x_proj input)
  __shared__ __align__(16) float dbl[4][4][64];    // dbc = x_proj output
  __shared__ __align__(16) float yzl[4][4][128];   // y*silu(z) (out_proj in)
  __shared__ __align__(16) float xnl[4][4][64];    // normed x (in_proj in)
  __shared__ __align__(16) float o6l[16][65];      // final out6 transpose

  const int wv = threadIdx.x >> 6, lane = threadIdx.x & 63;
  const int nb = blockIdx.x * 16;                  // block's first position
  const int b  = nb >> 12, l0 = nb & 4095;
  const int n0 = nb + wv * 4;                      // wave's first position
  const int d0 = lane, d1 = 64 + lane;

  // ---- stage rgb/dte tiles (coalesced) ----
  #pragma unroll
  for (int j = 0; j < 8; j++){
    int e = threadIdx.x + 256 * j;
    int w = e >> 10, c = (e >> 4) & 63, p = e & 15;
    const float* src = w ? dte : rgb;
    inT[w][c][p] = src[(size_t)b * 262144 + (size_t)c * 4096 + l0 + p];
  }
  __syncthreads();

  // ---- input 1x1 convs -> registers (channel = lane) ----
  float bR[4], bD[4];
  {
    float aR[4], aD[4];
    float biR = b1[lane], biD = b2[lane];
    #pragma unroll
    for (int p = 0; p < 4; p++){ aR[p] = biR; aD[p] = biD; }
    for (int c = 0; c < 64; c++){
      float wr = w1T[c*64 + lane], wd = w2T[c*64 + lane];
      #pragma unroll
      for (int p = 0; p < 4; p++){
        aR[p] += wr * inT[0][c][wv*4 + p];
        aD[p] += wd * inT[1][c][wv*4 + p];
      }
    }
    #pragma unroll
    for (int p = 0; p < 4; p++){ bR[p] = aR[p]; bD[p] = aD[p]; }
  }

  const float nw = normw[lane];
  const float cw00 = c1w[d0*3+0], cw01 = c1w[d0*3+1], cw02 = c1w[d0*3+2];
  const float cw10 = c1w[d1*3+0], cw11 = c1w[d1*3+1], cw12 = c1w[d1*3+2];
  const float cb0 = c1b[d0], cb1 = c1b[d1];
  const float tb0 = dtb[d0], tb1 = dtb[d1];
  const float dp0 = Dpw[d0], dp1 = Dpw[d1];

  float xn[4], zs0[4], zs1[4];
  float h0[4][16], h1[4][16];
  #pragma unroll
  for (int p = 0; p < 4; p++)
    #pragma unroll
    for (int s = 0; s < 16; s++){ h0[p][s] = 0.f; h1[p][s] = 0.f; }

  // ---- phase 0: rmsnorm(rgb) + in_proj -> xcp0, zs ----
  #pragma unroll
  for (int p = 0; p < 4; p++){
    float v = bR[p];
    float ss = v * v;
    for (int m = 32; m > 0; m >>= 1) ss += __shfl_xor(ss, m);
    v = v * rsqrtf(ss * (1.f/64.f) + 1e-5f) * nw;
    xn[p] = v; xnl[wv][p][lane] = v;
  }
  {
    float aX0[4] = {0,0,0,0}, aX1[4] = {0,0,0,0};
    float aZ0[4] = {0,0,0,0}, aZ1[4] = {0,0,0,0};
    for (int c = 0; c < 64; c++){
      float wx0 = ipT[c*256 + lane],       wx1 = ipT[c*256 + 64 + lane];
      float wz0 = ipT[c*256 + 128 + lane], wz1 = ipT[c*256 + 192 + lane];
      #pragma unroll
      for (int p = 0; p < 4; p++){
        float xv = xnl[wv][p][c];
        aX0[p] += wx0*xv; aX1[p] += wx1*xv; aZ0[p] += wz0*xv; aZ1[p] += wz1*xv;
      }
    }
    #pragma unroll
    for (int p = 0; p < 4; p++){
      int n = n0 + p;
      xcp0[(size_t)n*128 + lane]      = aX0[p];
      xcp0[(size_t)n*128 + 64 + lane] = aX1[p];
      zs0[p] = silu_f(aZ0[p]); zs1[p] = silu_f(aZ1[p]);
    }
  }
  gsync(bar, 0);

  // ---- 6 mamba blocks ----
  const float4* A4 = (const float4*)Aneg;
  #pragma unroll 1
  for (int k = 0; k < 6; k++){
    const float* xA = (k & 1) ? xcp1 : xcp0;
    float*       xB = (k & 1) ? xcp0 : xcp1;

    // depthwise conv1d (radius 1 within batch) + silu
    float xc0[4], xc1[4];
    #pragma unroll
    for (int p = 0; p < 4; p++){
      int n = n0 + p, l = n & 4095;
      const float* xr = xA + (size_t)n * 128;
      float am0 = 0.f, am1 = 0.f, ap0 = 0.f, ap1 = 0.f;
      if (l > 0)    { am0 = xr[d0 - 128]; am1 = xr[d1 - 128]; }
      float a00 = xr[d0], a01 = xr[d1];
      if (l < 4095) { ap0 = xr[d0 + 128]; ap1 = xr[d1 + 128]; }
      float v0 = silu_f(cw00*am0 + cw01*a00 + cw02*ap0 + cb0);
      float v1 = silu_f(cw10*am1 + cw11*a01 + cw12*ap1 + cb1);
      xc0[p] = v0; xc1[p] = v1;
      xcl[wv][p][d0] = v0; xcl[wv][p][d1] = v1;
    }

    // x_proj -> dbc[o=lane]
    {
      float xa[4] = {0,0,0,0};
      for (int d = 0; d < 128; d++){
        float w = xpT[d*64 + lane];
        #pragma unroll
        for (int p = 0; p < 4; p++) xa[p] += w * xcl[wv][p][d];
      }
      #pragma unroll
      for (int p = 0; p < 4; p++) dbl[wv][p][lane] = xa[p];
    }

    // dt_proj + softplus
    float dl0[4], dl1[4];
    {
      float da0[4], da1[4];
      #pragma unroll
      for (int p = 0; p < 4; p++){ da0[p] = tb0; da1[p] = tb1; }
      for (int r = 0; r < 32; r++){
        float w0 = dtT[r*128 + d0], w1 = dtT[r*128 + d1];
        #pragma unroll
        for (int p = 0; p < 4; p++){
          float bv = dbl[wv][p][r];
          da0[p] += w0 * bv; da1[p] += w1 * bv;
        }
      }
      #pragma unroll
      for (int p = 0; p < 4; p++){ dl0[p] = softplus_f(da0[p]); dl1[p] = softplus_f(da1[p]); }
    }

    // SSM state update (h in registers) + y
    #pragma unroll
    for (int p = 0; p < 4; p++){
      float y0 = 0.f, y1 = 0.f;
      float bx0 = dl0[p] * xc0[p], bx1 = dl1[p] * xc1[p];
      #pragma unroll
      for (int q = 0; q < 4; q++){
        float4 a0 = A4[d0*4 + q];
        float4 a1 = A4[d1*4 + q];
        float4 bq = *(const float4*)&dbl[wv][p][32 + q*4];
        float4 cq = *(const float4*)&dbl[wv][p][48 + q*4];
        h0[p][q*4+0] = __expf(dl0[p]*a0.x)*h0[p][q*4+0] + bx0*bq.x; y0 = fmaf(h0[p][q*4+0], cq.x, y0);
        h0[p][q*4+1] = __expf(dl0[p]*a0.y)*h0[p][q*4+1] + bx0*bq.y; y0 = fmaf(h0[p][q*4+1], cq.y, y0);
        h0[p][q*4+2] = __expf(dl0[p]*a0.z)*h0[p][q*4+2] + bx0*bq.z; y0 = fmaf(h0[p][q*4+2], cq.z, y0);
        h0[p][q*4+3] = __expf(dl0[p]*a0.w)*h0[p][q*4+3] + bx0*bq.w; y0 = fmaf(h0[p][q*4+3], cq.w, y0);
        h1[p][q*4+0] = __expf(dl1[p]*a1.x)*h1[p][q*4+0] + bx1*bq.x; y1 = fmaf(h1[p][q*4+0], cq.x, y1);
        h1[p][q*4+1] = __expf(dl1[p]*a1.y)*h1[p][q*4+1] + bx1*bq.y; y1 = fmaf(h1[p][q*4+1], cq.y, y1);
        h1[p][q*4+2] = __expf(dl1[p]*a1.z)*h1[p][q*4+2] + bx1*bq.z; y1 = fmaf(h1[p][q*4+2], cq.z, y1);
        h1[p][q*4+3] = __expf(dl1[p]*a1.w)*h1[p][q*4+3] + bx1*bq.w; y1 = fmaf(h1[p][q*4+3], cq.w, y1);
      }
      y0 += dp0 * xc0[p];
      y1 += dp1 * xc1[p];
      yzl[wv][p][d0] = y0 * zs0[p];
      yzl[wv][p][d1] = y1 * zs1[p];
    }

    // out_proj
    float oa[4] = {0,0,0,0};
    for (int d = 0; d < 128; d++){
      float w = opT[d*64 + lane];
      #pragma unroll
      for (int p = 0; p < 4; p++) oa[p] += w * yzl[wv][p][d];
    }

    if (k < 5){
      // residual + next base, rmsnorm, in_proj -> xB, zs
      #pragma unroll
      for (int p = 0; p < 4; p++){
        float v = oa[p] + xn[p] + ((k & 1) ? bR[p] : bD[p]);
        float ss = v * v;
        for (int m = 32; m > 0; m >>= 1) ss += __shfl_xor(ss, m);
        v = v * rsqrtf(ss * (1.f/64.f) + 1e-5f) * nw;
        xn[p] = v; xnl[wv][p][lane] = v;
      }
      float aX0[4] = {0,0,0,0}, aX1[4] = {0,0,0,0};
      float aZ0[4] = {0,0,0,0}, aZ1[4] = {0,0,0,0};
      for (int c = 0; c < 64; c++){
        float wx0 = ipT[c*256 + lane],       wx1 = ipT[c*256 + 64 + lane];
        float wz0 = ipT[c*256 + 128 + lane], wz1 = ipT[c*256 + 192 + lane];
        #pragma unroll
        for (int p = 0; p < 4; p++){
          float xv = xnl[wv][p][c];
          aX0[p] += wx0*xv; aX1[p] += wx1*xv; aZ0[p] += wz0*xv; aZ1[p] += wz1*xv;
        }
      }
      #pragma unroll
      for (int p = 0; p < 4; p++){
        int n = n0 + p;
        xB[(size_t)n*128 + lane]      = aX0[p];
        xB[(size_t)n*128 + 64 + lane] = aX1[p];
        zs0[p] = silu_f(aZ0[p]); zs1[p] = silu_f(aZ1[p]);
      }
      gsync(bar, k + 1);
    } else {
      // finalize: write h (fp32, float4) + out6 -> LDS for conv3
      #pragma unroll
      for (int p = 0; p < 4; p++){
        int n = n0 + p;
        float4* hp0 = (float4*)(hout + (size_t)n*2048 + (size_t)d0*16);
        float4* hp1 = (float4*)(hout + (size_t)n*2048 + (size_t)d1*16);
        #pragma unroll
        for (int q = 0; q < 4; q++){
          float4 v; v.x=h0[p][q*4+0]; v.y=h0[p][q*4+1]; v.z=h0[p][q*4+2]; v.w=h0[p][q*4+3];
          hp0[q] = v;
          float4 w; w.x=h1[p][q*4+0]; w.y=h1[p][q*4+1]; w.z=h1[p][q*4+2]; w.w=h1[p][q*4+3];
          hp1[q] = w;
        }
        o6l[wv*4 + p][lane] = oa[p] + xn[p];
      }
      __syncthreads();
      // conv3: out[b][o][l] = b3[o] + sum_c w3[o][c] * out6[c]
      int o  = threadIdx.x >> 2;
      int pb = (threadIdx.x & 3) * 4;
      float ac0 = b3[o], ac1 = ac0, ac2 = ac0, ac3 = ac0;
      for (int c = 0; c < 64; c++){
        float w = w3T[c*64 + o];
        ac0 += w * o6l[pb + 0][c];
        ac1 += w * o6l[pb + 1][c];
        ac2 += w * o6l[pb + 2][c];
        ac3 += w * o6l[pb + 3][c];
      }
      size_t ob = (size_t)b * 262144 + (size_t)o * 4096 + l0 + pb;
      outc[ob + 0] = ac0; outc[ob + 1] = ac1; outc[ob + 2] = ac2; outc[ob + 3] = ac3;
    }
  }
}

extern "C" void kernel_launch(void* const* d_in, const int* in_sizes, int n_in,
                              void* d_out, int out_size, void* d_ws, size_t ws_size,
                              hipStream_t stream)
{
  const float* rgb  = (const float*)d_in[0];
  const float* dte  = (const float*)d_in[1];
  const float* w1   = (const float*)d_in[2];
  const float* b1   = (const float*)d_in[3];
  const float* w2   = (const float*)d_in[4];
  const float* b2   = (const float*)d_in[5];
  const float* w3   = (const float*)d_in[6];
  const float* b3   = (const float*)d_in[7];
  const float* nrm  = (const float*)d_in[8];
  const float* ipw  = (const float*)d_in[9];
  const float* c1w  = (const float*)d_in[10];
  const float* c1b  = (const float*)d_in[11];
  const float* xpw  = (const float*)d_in[12];
  const float* dtw  = (const float*)d_in[13];
  const float* dtb  = (const float*)d_in[14];
  const float* alog = (const float*)d_in[15];
  const float* Dpw  = (const float*)d_in[16];
  const float* opw  = (const float*)d_in[17];

  float* outc = (float*)d_out;
  float* hout = outc + 524288;

  float* ws   = (float*)d_ws;
  float* xcp0 = ws;                     // [N,128] ping  (4 MB)
  float* xcp1 = ws + 1048576;           // [N,128] pong  (4 MB)
  float* wb   = ws + 2097152;
  float* ipT  = wb;                     // [64][256]
  float* xpT  = wb + 16384;             // [128][64]
  float* dtT  = wb + 24576;             // [32][128]
  float* opT  = wb + 28672;             // [128][64]
  float* w1T  = wb + 36864;             // [64][64]
  float* w2T  = wb + 40960;
  float* w3T  = wb + 45056;
  float* Aneg = wb + 49152;             // [128][16]
  unsigned* bar = (unsigned*)(wb + 51200);

  hipMemsetAsync((void*)bar, 0, 64, stream);
  k_prep<<<64, 256, 0, stream>>>(ipw, xpw, dtw, opw, w1, w2, w3, alog,
                                 ipT, xpT, dtT, opT, w1T, w2T, w3T, Aneg);
  k_fused<<<NBLK, 256, 0, stream>>>(rgb, dte, b1, b2, w1T, w2T, nrm, ipT,
                                    xpT, dtT, opT, Aneg, c1w, c1b, dtb, Dpw,
                                    w3T, b3, xcp0, xcp1, bar, outc, hout);
}

// Round 4
// 364.444 us; speedup vs baseline: 2.9349x; 2.9349x over previous
//
#include <hip/hip_runtime.h>

typedef unsigned short u16;
typedef unsigned int u32;

#define LSEQ 4096
#define NPOS 8192

__device__ __forceinline__ float bf2f(u16 u){
  union { u32 i; float f; } v; v.i = ((u32)u) << 16; return v.f;
}
__device__ __forceinline__ u16 f2bf(float f){
  union { float f; u32 i; } v; v.f = f;
  u32 x = v.i;
  return (u16)((x + 0x7fffu + ((x >> 16) & 1u)) >> 16);
}
__device__ __forceinline__ float2 up2(u32 u){
  union { u32 i; float f; } a, b;
  a.i = u << 16; b.i = u & 0xffff0000u;
  float2 r; r.x = a.f; r.y = b.f; return r;
}
__device__ __forceinline__ u32 pk2(float a, float b){
  return (u32)f2bf(a) | ((u32)f2bf(b) << 16);
}
__device__ __forceinline__ float silu_f(float x){ return x / (1.f + __expf(-x)); }
__device__ __forceinline__ float softplus_f(float x){
  return fmaxf(x, 0.f) + log1pf(__expf(-fabsf(x)));
}

// ---- transpose weights, A = -exp(A_log) --------------------------------
__global__ __launch_bounds__(256) void k_prep(
    const float* __restrict__ ipw, const float* __restrict__ xpw,
    const float* __restrict__ dtw, const float* __restrict__ opw,
    const float* __restrict__ w1, const float* __restrict__ w2,
    const float* __restrict__ w3, const float* __restrict__ alog,
    float* __restrict__ ipT, float* __restrict__ xpT,
    float* __restrict__ dtT, float* __restrict__ opT,
    float* __restrict__ w1T, float* __restrict__ w2T,
    float* __restrict__ w3T, float* __restrict__ Aneg)
{
  int t = blockIdx.x * 256 + threadIdx.x;
  if (t < 16384){ int o = t >> 6, c = t & 63; ipT[c * 256 + o] = ipw[t]; }
  if (t < 8192){ int o = t >> 7, d = t & 127; xpT[d * 64 + o] = xpw[t]; }
  if (t < 4096){ int d = t >> 5, r = t & 31; dtT[r * 128 + d] = dtw[t]; }
  if (t < 8192){ int o = t >> 7, d = t & 127; opT[d * 64 + o] = opw[t]; }
  if (t < 4096){ int o = t >> 6, c = t & 63;
                 w1T[c*64+o] = w1[t]; w2T[c*64+o] = w2[t]; w3T[c*64+o] = w3[t]; }
  if (t < 2048){ Aneg[t] = -__expf(alog[t]); }
}

// ---- input 1x1 convs, LDS-tiled: [B,C,L] -> [N,64] position-major ------
// 256 blocks: bit0 = which tensor, rest = 64-position tile index.
__global__ __launch_bounds__(256) void k_convin(
    const float* __restrict__ rgb, const float* __restrict__ dte,
    const float* __restrict__ w1T, const float* __restrict__ b1,
    const float* __restrict__ w2T, const float* __restrict__ b2,
    float* __restrict__ rgbp, float* __restrict__ dtep)
{
  __shared__ __align__(16) float xt[64][64];
  __shared__ __align__(16) float ot[64][65];
  const int tid = threadIdx.x;
  const int which = blockIdx.x & 1;
  const int n0 = (blockIdx.x >> 1) * 64;
  const int b = n0 >> 12, l0 = n0 & 4095;
  const float* src = which ? dte : rgb;
  const float* wT  = which ? w2T : w1T;
  const float* bb  = which ? b2 : b1;
  float* o = which ? dtep : rgbp;

  #pragma unroll
  for (int j = 0; j < 16; j++){
    int idx = tid + 256 * j;
    int c = idx >> 6, p = idx & 63;
    xt[c][p] = src[(size_t)b * 262144 + (size_t)c * 4096 + l0 + p];
  }
  __syncthreads();

  const int pos = tid & 63;
  const int cb  = (tid >> 6) * 16;
  float acc[16];
  #pragma unroll
  for (int j = 0; j < 16; j++) acc[j] = bb[cb + j];
  for (int c = 0; c < 64; c++){
    float xv = xt[c][pos];
    #pragma unroll
    for (int j = 0; j < 16; j++) acc[j] += wT[c*64 + cb + j] * xv;
  }
  #pragma unroll
  for (int j = 0; j < 16; j++) ot[pos][cb + j] = acc[j];
  __syncthreads();
  #pragma unroll
  for (int j = 0; j < 16; j++){
    int idx = tid + 256 * j;
    int p = idx >> 6, c = idx & 63;
    o[(size_t)(n0 + p)*64 + c] = ot[p][c];
  }
}

// ---- block-0 pre: rmsnorm + in_proj (one wave = 2 positions) -----------
__global__ __launch_bounds__(256) void k_pre(
    const float* __restrict__ xin, const float* __restrict__ normw,
    const float* __restrict__ ipT,
    float* __restrict__ xn, float* __restrict__ xcp, float* __restrict__ zs)
{
  __shared__ __align__(16) float xnl[4][2][64];
  const int wv = threadIdx.x >> 6, lane = threadIdx.x & 63;
  const int n0 = (blockIdx.x * 4 + wv) * 2;
  float nw = normw[lane];
  #pragma unroll
  for (int p = 0; p < 2; p++){
    int n = n0 + p;
    float v = xin[(size_t)n*64 + lane];
    float ss = v * v;
    for (int m = 32; m > 0; m >>= 1) ss += __shfl_xor(ss, m);
    v = v * rsqrtf(ss * (1.f/64.f) + 1e-5f) * nw;
    xn[(size_t)n*64 + lane] = v;
    xnl[wv][p][lane] = v;
  }
  float ac[2][4] = {};
  for (int c = 0; c < 64; c++){
    float w0 = ipT[c*256 + lane],       w1 = ipT[c*256 + 64 + lane];
    float w2 = ipT[c*256 + 128 + lane], w3 = ipT[c*256 + 192 + lane];
    #pragma unroll
    for (int p = 0; p < 2; p++){
      float xv = xnl[wv][p][c];
      ac[p][0] += w0*xv; ac[p][1] += w1*xv; ac[p][2] += w2*xv; ac[p][3] += w3*xv;
    }
  }
  #pragma unroll
  for (int p = 0; p < 2; p++){
    int n = n0 + p;
    xcp[(size_t)n*128 + lane]      = ac[p][0];
    xcp[(size_t)n*128 + 64 + lane] = ac[p][1];
    zs[(size_t)n*128 + lane]       = silu_f(ac[p][2]);
    zs[(size_t)n*128 + 64 + lane]  = silu_f(ac[p][3]);
  }
}

// ---- one Mamba block (+ fused next-block rmsnorm/in_proj) --------------
// one wave = 2 positions; lane owns d0=lane, d1=64+lane of d_inner.
// Intermediate h is bf16 (hbf); final phase writes fp32 to hfin (d_out).
__global__ __launch_bounds__(256) void k_step(
    const float* __restrict__ xcpA, float* __restrict__ xcpB,
    float* __restrict__ zs, float* __restrict__ xn,
    u16* __restrict__ hbf, float* __restrict__ hfin,
    const float* __restrict__ base_next,
    const float* __restrict__ xpT, const float* __restrict__ dtT,
    const float* __restrict__ opT, const float* __restrict__ Aneg,
    const float* __restrict__ c1w, const float* __restrict__ c1b,
    const float* __restrict__ dtb, const float* __restrict__ Dpw,
    const float* __restrict__ normw, const float* __restrict__ ipT,
    int hasH, int fusePre)
{
  __shared__ __align__(16) float xcl[4][2][128];
  __shared__ __align__(16) float dbl[4][2][64];
  __shared__ __align__(16) float yzl[4][2][128];
  __shared__ __align__(16) float xnl[4][2][64];
  const int wv = threadIdx.x >> 6, lane = threadIdx.x & 63;
  const int n0 = (blockIdx.x * 4 + wv) * 2;
  const int d0 = lane, d1 = 64 + lane;

  float cw00 = c1w[d0*3+0], cw01 = c1w[d0*3+1], cw02 = c1w[d0*3+2];
  float cw10 = c1w[d1*3+0], cw11 = c1w[d1*3+1], cw12 = c1w[d1*3+2];
  float cb0 = c1b[d0], cb1 = c1b[d1];

  // depthwise conv (radius 1 over l within batch) + silu
  float xc0[2], xc1[2];
  #pragma unroll
  for (int p = 0; p < 2; p++){
    int n = n0 + p, l = n & 4095;
    const float* xr = xcpA + (size_t)n * 128;
    float am0 = 0.f, am1 = 0.f, ap0 = 0.f, ap1 = 0.f;
    if (l > 0)    { am0 = xr[d0 - 128]; am1 = xr[d1 - 128]; }
    float a00 = xr[d0], a01 = xr[d1];
    if (l < 4095) { ap0 = xr[d0 + 128]; ap1 = xr[d1 + 128]; }
    float v0 = silu_f(cw00*am0 + cw01*a00 + cw02*ap0 + cb0);
    float v1 = silu_f(cw10*am1 + cw11*a01 + cw12*ap1 + cb1);
    xc0[p] = v0; xc1[p] = v1;
    xcl[wv][p][d0] = v0; xcl[wv][p][d1] = v1;
  }

  // x_proj -> dbc[o=lane]
  {
    float xa[2] = {0,0};
    for (int d = 0; d < 128; d++){
      float w = xpT[d*64 + lane];
      #pragma unroll
      for (int p = 0; p < 2; p++) xa[p] += w * xcl[wv][p][d];
    }
    #pragma unroll
    for (int p = 0; p < 2; p++) dbl[wv][p][lane] = xa[p];
  }

  // dt_proj + softplus
  float dl0[2], dl1[2];
  {
    float tb0 = dtb[d0], tb1 = dtb[d1];
    float da0[2] = {tb0, tb0}, da1[2] = {tb1, tb1};
    for (int r = 0; r < 32; r++){
      float w0 = dtT[r*128 + d0], w1 = dtT[r*128 + d1];
      #pragma unroll
      for (int p = 0; p < 2; p++){
        float bv = dbl[wv][p][r];
        da0[p] += w0 * bv; da1[p] += w1 * bv;
      }
    }
    #pragma unroll
    for (int p = 0; p < 2; p++){ dl0[p] = softplus_f(da0[p]); dl1[p] = softplus_f(da1[p]); }
  }

  float an0[16], an1[16];
  {
    const float4* A0 = (const float4*)(Aneg + d0*16);
    const float4* A1 = (const float4*)(Aneg + d1*16);
    #pragma unroll
    for (int q = 0; q < 4; q++){
      float4 a = A0[q]; an0[q*4+0]=a.x; an0[q*4+1]=a.y; an0[q*4+2]=a.z; an0[q*4+3]=a.w;
      float4 b = A1[q]; an1[q*4+0]=b.x; an1[q*4+1]=b.y; an1[q*4+2]=b.z; an1[q*4+3]=b.w;
    }
  }
  float dp0 = Dpw[d0], dp1 = Dpw[d1];

  // h update (bf16 intermediate in ws; fp32 final to d_out) + y
  #pragma unroll 1
  for (int p = 0; p < 2; p++){
    int n = n0 + p;
    float Bm[16], Cm[16];
    {
      const float4* bb = (const float4*)&dbl[wv][p][32];
      const float4* cc = (const float4*)&dbl[wv][p][48];
      #pragma unroll
      for (int q = 0; q < 4; q++){
        float4 a = bb[q]; Bm[q*4+0]=a.x; Bm[q*4+1]=a.y; Bm[q*4+2]=a.z; Bm[q*4+3]=a.w;
        float4 b = cc[q]; Cm[q*4+0]=b.x; Cm[q*4+1]=b.y; Cm[q*4+2]=b.z; Cm[q*4+3]=b.w;
      }
    }
    u16* hp0 = hbf + ((size_t)n*2048 + (size_t)d0*16);
    u16* hp1 = hbf + ((size_t)n*2048 + (size_t)d1*16);
    float h0[16], h1[16];
    if (hasH){
      #pragma unroll
      for (int q = 0; q < 2; q++){
        uint4 v = ((const uint4*)hp0)[q];
        float2 t0=up2(v.x), t1=up2(v.y), t2=up2(v.z), t3=up2(v.w);
        h0[q*8+0]=t0.x; h0[q*8+1]=t0.y; h0[q*8+2]=t1.x; h0[q*8+3]=t1.y;
        h0[q*8+4]=t2.x; h0[q*8+5]=t2.y; h0[q*8+6]=t3.x; h0[q*8+7]=t3.y;
        uint4 w = ((const uint4*)hp1)[q];
        float2 s0=up2(w.x), s1=up2(w.y), s2=up2(w.z), s3=up2(w.w);
        h1[q*8+0]=s0.x; h1[q*8+1]=s0.y; h1[q*8+2]=s1.x; h1[q*8+3]=s1.y;
        h1[q*8+4]=s2.x; h1[q*8+5]=s2.y; h1[q*8+6]=s3.x; h1[q*8+7]=s3.y;
      }
    } else {
      #pragma unroll
      for (int s = 0; s < 16; s++){ h0[s]=0.f; h1[s]=0.f; }
    }
    float y0 = 0.f, y1 = 0.f;
    float bx0 = dl0[p] * xc0[p], bx1 = dl1[p] * xc1[p];
    #pragma unroll
    for (int s = 0; s < 16; s++){
      h0[s] = __expf(dl0[p]*an0[s])*h0[s] + bx0*Bm[s];
      y0 = fmaf(h0[s], Cm[s], y0);
      h1[s] = __expf(dl1[p]*an1[s])*h1[s] + bx1*Bm[s];
      y1 = fmaf(h1[s], Cm[s], y1);
    }
    if (fusePre){
      #pragma unroll
      for (int q = 0; q < 2; q++){
        uint4 v;
        v.x = pk2(h0[q*8+0], h0[q*8+1]); v.y = pk2(h0[q*8+2], h0[q*8+3]);
        v.z = pk2(h0[q*8+4], h0[q*8+5]); v.w = pk2(h0[q*8+6], h0[q*8+7]);
        ((uint4*)hp0)[q] = v;
        uint4 w;
        w.x = pk2(h1[q*8+0], h1[q*8+1]); w.y = pk2(h1[q*8+2], h1[q*8+3]);
        w.z = pk2(h1[q*8+4], h1[q*8+5]); w.w = pk2(h1[q*8+6], h1[q*8+7]);
        ((uint4*)hp1)[q] = w;
      }
    } else {
      float4* f0 = (float4*)(hfin + (size_t)n*2048 + (size_t)d0*16);
      float4* f1 = (float4*)(hfin + (size_t)n*2048 + (size_t)d1*16);
      #pragma unroll
      for (int q = 0; q < 4; q++){
        float4 v; v.x=h0[q*4+0]; v.y=h0[q*4+1]; v.z=h0[q*4+2]; v.w=h0[q*4+3];
        f0[q] = v;
        float4 w; w.x=h1[q*4+0]; w.y=h1[q*4+1]; w.z=h1[q*4+2]; w.w=h1[q*4+3];
        f1[q] = w;
      }
    }
    y0 += dp0 * xc0[p];
    y1 += dp1 * xc1[p];
    yzl[wv][p][d0] = y0 * zs[(size_t)n*128 + d0];
    yzl[wv][p][d1] = y1 * zs[(size_t)n*128 + d1];
  }

  // out_proj
  float oa[2] = {0,0};
  for (int d = 0; d < 128; d++){
    float w = opT[d*64 + lane];
    #pragma unroll
    for (int p = 0; p < 2; p++) oa[p] += w * yzl[wv][p][d];
  }

  float nw = normw[lane];
  if (fusePre){
    #pragma unroll
    for (int p = 0; p < 2; p++){
      int n = n0 + p;
      float v = oa[p] + xn[(size_t)n*64 + lane] + base_next[(size_t)n*64 + lane];
      float ss = v * v;
      for (int m = 32; m > 0; m >>= 1) ss += __shfl_xor(ss, m);
      v = v * rsqrtf(ss * (1.f/64.f) + 1e-5f) * nw;
      xn[(size_t)n*64 + lane] = v;
      xnl[wv][p][lane] = v;
    }
    float ac[2][4] = {};
    for (int c = 0; c < 64; c++){
      float w0 = ipT[c*256 + lane],       w1 = ipT[c*256 + 64 + lane];
      float w2 = ipT[c*256 + 128 + lane], w3 = ipT[c*256 + 192 + lane];
      #pragma unroll
      for (int p = 0; p < 2; p++){
        float xv = xnl[wv][p][c];
        ac[p][0] += w0*xv; ac[p][1] += w1*xv; ac[p][2] += w2*xv; ac[p][3] += w3*xv;
      }
    }
    #pragma unroll
    for (int p = 0; p < 2; p++){
      int n = n0 + p;
      xcpB[(size_t)n*128 + lane]      = ac[p][0];
      xcpB[(size_t)n*128 + 64 + lane] = ac[p][1];
      zs[(size_t)n*128 + lane]        = silu_f(ac[p][2]);
      zs[(size_t)n*128 + 64 + lane]   = silu_f(ac[p][3]);
    }
  } else {
    #pragma unroll
    for (int p = 0; p < 2; p++){
      int n = n0 + p;
      xcpB[(size_t)n*64 + lane] = oa[p] + xn[(size_t)n*64 + lane];
    }
  }
}

// ---- final conv1x1, transpose [N,64] -> [B,64,L] -----------------------
__global__ __launch_bounds__(256) void k_conv3(
    const float* __restrict__ out6, const float* __restrict__ w3T,
    const float* __restrict__ b3, float* __restrict__ out)
{
  __shared__ __align__(16) float t[64][65];
  const int tid = threadIdx.x;
  const int n0 = blockIdx.x * 64;
  #pragma unroll
  for (int i = 0; i < 16; i++){
    int idx = tid + 256*i;
    int r = idx >> 6, c = idx & 63;
    t[r][c] = out6[(size_t)(n0 + r)*64 + c];
  }
  __syncthreads();
  const int i = tid & 63;
  const int cb = (tid >> 6) * 16;
  float acc[16];
  #pragma unroll
  for (int j = 0; j < 16; j++) acc[j] = b3[cb + j];
  for (int o = 0; o < 64; o++){
    float xv = t[i][o];
    #pragma unroll
    for (int j = 0; j < 16; j++) acc[j] += w3T[o*64 + cb + j] * xv;
  }
  const int b = n0 >> 12;
  const int l = (n0 & 4095) + i;
  #pragma unroll
  for (int j = 0; j < 16; j++)
    out[(size_t)b*262144 + (size_t)(cb + j)*4096 + l] = acc[j];
}

extern "C" void kernel_launch(void* const* d_in, const int* in_sizes, int n_in,
                              void* d_out, int out_size, void* d_ws, size_t ws_size,
                              hipStream_t stream)
{
  const float* rgb  = (const float*)d_in[0];
  const float* dte  = (const float*)d_in[1];
  const float* w1   = (const float*)d_in[2];
  const float* b1   = (const float*)d_in[3];
  const float* w2   = (const float*)d_in[4];
  const float* b2   = (const float*)d_in[5];
  const float* w3   = (const float*)d_in[6];
  const float* b3   = (const float*)d_in[7];
  const float* nrm  = (const float*)d_in[8];
  const float* ipw  = (const float*)d_in[9];
  const float* c1w  = (const float*)d_in[10];
  const float* c1b  = (const float*)d_in[11];
  const float* xpw  = (const float*)d_in[12];
  const float* dtw  = (const float*)d_in[13];
  const float* dtb  = (const float*)d_in[14];
  const float* alog = (const float*)d_in[15];
  const float* Dpw  = (const float*)d_in[16];
  const float* opw  = (const float*)d_in[17];

  float* outc = (float*)d_out;
  float* hfin = outc + 524288;          // final fp32 h lives in d_out

  float* ws   = (float*)d_ws;
  float* xcp0 = ws;                     // [N,128] ping
  float* xcp1 = ws + 1048576;           // [N,128] pong
  float* rgbp = ws + 2097152;           // [N,64]
  float* dtep = ws + 2621440;           // [N,64]
  float* xnb  = ws + 3145728;           // [N,64]
  float* zsb  = ws + 3670016;           // [N,128]
  float* wb   = ws + 4718592;           // transposed weights
  float* ipT  = wb;                     // [64][256]
  float* xpT  = wb + 16384;             // [128][64]
  float* dtT  = wb + 24576;             // [32][128]
  float* opT  = wb + 28672;             // [128][64]
  float* w1T  = wb + 36864;             // [64][64]
  float* w2T  = wb + 40960;
  float* w3T  = wb + 45056;
  float* Aneg = wb + 49152;             // [128][16]
  u16*   hbf  = (u16*)(ws + 4769792);   // [N,128,16] bf16 intermediate h (33.5 MB)

  k_prep<<<64, 256, 0, stream>>>(ipw, xpw, dtw, opw, w1, w2, w3, alog,
                                 ipT, xpT, dtT, opT, w1T, w2T, w3T, Aneg);
  k_convin<<<256, 256, 0, stream>>>(rgb, dte, w1T, b1, w2T, b2, rgbp, dtep);
  k_pre<<<1024, 256, 0, stream>>>(rgbp, nrm, ipT, xnb, xcp0, zsb);

  float* xa[2] = {xcp0, xcp1};
  for (int k = 0; k < 6; k++){
    const float* base = (k == 5) ? rgbp /*unused*/ : ((k & 1) ? rgbp : dtep);
    k_step<<<1024, 256, 0, stream>>>(xa[k & 1], xa[(k & 1) ^ 1], zsb, xnb,
                                     hbf, hfin, base,
                                     xpT, dtT, opT, Aneg, c1w, c1b, dtb, Dpw,
                                     nrm, ipT, (k > 0) ? 1 : 0, (k < 5) ? 1 : 0);
  }
  k_conv3<<<128, 256, 0, stream>>>(xcp0, w3T, b3, outc);
}